// Round 2
// baseline (91.984 us; speedup 1.0000x reference)
//
#include <hip/hip_runtime.h>

#define C_ 128
#define K_ 64
#define H_ 40
#define W_ 30
#define N_ 4
#define HW_ 1200          // H_*W_
#define P_ 5
#define OH_ 36            // H_+1-P_
#define OW_ 26            // W_+1-P_
#define OHW_ 936
#define INV25 (1.0f/25.0f)

// DPP helper: returns value moved per CTRL, 0-filled at row bounds.
// row_shl:N = 0x100+N ; row_shr:N = 0x110+N  (16-lane rows, bound_ctrl=0)
template<int CTRL>
__device__ __forceinline__ float dpp0f(float v) {
  return __int_as_float(__builtin_amdgcn_update_dpp(
      0, __float_as_int(v), CTRL, 0xF, 0xF, true));
}
// swap 16-lane rows pairwise (lane ^= 16)
__device__ __forceinline__ float swz_x16(float v) {
  return __int_as_float(__builtin_amdgcn_ds_swizzle(__float_as_int(v), 0x401F));
}

// ---------------------------------------------------------------------------
// K1 v3: 4 contiguous pixels per block, 256 threads, grid = 1200.
// All x/xn traffic is float4 over the pixel dim. Norm: redundant per-wave
// shfl reduce (no barrier). Conv: thread=(k, cq); wt staged [k][c] in LDS.
// ---------------------------------------------------------------------------
__global__ __launch_bounds__(256) void k1_prep(
    const float* __restrict__ x, const float* __restrict__ cw,
    float* __restrict__ xn, float* __restrict__ sa)
{
  __shared__ float wt[K_][132];   // [k][c] pad->132 (rows 16B-aligned), 33 KB
  __shared__ float ls[K_][5];     // logits [k][pixel] padded

  const int tid  = threadIdx.x;
  const int bid  = blockIdx.x;
  const int n    = bid / 300;
  const int rem  = (bid - n*300) * 4;          // 4 contiguous pixels
  const float* __restrict__ xb = x + (size_t)n*C_*HW_ + rem;

  // stage conv_w -> LDS, coalesced float4 (2048 float4s)
  for (int e = tid; e < K_*C_/4; e += 256) {
    const int k  = e >> 5;
    const int c4 = (e & 31) << 2;
    const float4 v = *(const float4*)(cw + k*C_ + c4);
    *(float4*)&wt[k][c4] = v;
  }

  // per-pixel L2 norms, computed redundantly by every wave (no barrier)
  const int lane = tid & 63;
  const int wv   = tid >> 6;
  const float4 a0 = *(const float4*)(xb + (size_t)lane*HW_);
  const float4 a1 = *(const float4*)(xb + (size_t)(lane + 64)*HW_);
  float sx = a0.x*a0.x + a1.x*a1.x;
  float sy = a0.y*a0.y + a1.y*a1.y;
  float sz = a0.z*a0.z + a1.z*a1.z;
  float sw = a0.w*a0.w + a1.w*a1.w;
  #pragma unroll
  for (int m = 1; m < 64; m <<= 1) {
    sx += __shfl_xor(sx, m, 64);
    sy += __shfl_xor(sy, m, 64);
    sz += __shfl_xor(sz, m, 64);
    sw += __shfl_xor(sw, m, 64);
  }
  const float rnx = 1.f / fmaxf(sqrtf(sx), 1e-12f);
  const float rny = 1.f / fmaxf(sqrtf(sy), 1e-12f);
  const float rnz = 1.f / fmaxf(sqrtf(sz), 1e-12f);
  const float rnw = 1.f / fmaxf(sqrtf(sw), 1e-12f);

  // write xn' = (x/||x||) * (1/25), pre-scaled for k2
  if (wv == 0) {
    float4 o;
    o.x = a0.x*rnx*INV25; o.y = a0.y*rny*INV25;
    o.z = a0.z*rnz*INV25; o.w = a0.w*rnw*INV25;
    *(float4*)(xn + ((size_t)n*C_ + lane)*HW_ + rem) = o;
  } else if (wv == 1) {
    float4 o;
    o.x = a1.x*rnx*INV25; o.y = a1.y*rny*INV25;
    o.z = a1.z*rnz*INV25; o.w = a1.w*rnw*INV25;
    *(float4*)(xn + ((size_t)n*C_ + lane + 64)*HW_ + rem) = o;
  }

  __syncthreads();   // wt ready

  // conv: thread (k = tid>>2, cq = tid&3) accumulates 32 channels x 4 pixels
  const int k  = tid >> 2;
  const int cq = tid & 3;
  const float* __restrict__ xc = xb + (size_t)cq*32*HW_;
  float ax = 0.f, ay = 0.f, az = 0.f, aw = 0.f;
  #pragma unroll
  for (int j = 0; j < 8; ++j) {
    const float4 w4 = *(const float4*)&wt[k][cq*32 + j*4];
    const float4 x0 = *(const float4*)(xc + (size_t)(j*4 + 0)*HW_);
    const float4 x1 = *(const float4*)(xc + (size_t)(j*4 + 1)*HW_);
    const float4 x2 = *(const float4*)(xc + (size_t)(j*4 + 2)*HW_);
    const float4 x3 = *(const float4*)(xc + (size_t)(j*4 + 3)*HW_);
    ax = fmaf(w4.x, x0.x, ax); ay = fmaf(w4.x, x0.y, ay);
    az = fmaf(w4.x, x0.z, az); aw = fmaf(w4.x, x0.w, aw);
    ax = fmaf(w4.y, x1.x, ax); ay = fmaf(w4.y, x1.y, ay);
    az = fmaf(w4.y, x1.z, az); aw = fmaf(w4.y, x1.w, aw);
    ax = fmaf(w4.z, x2.x, ax); ay = fmaf(w4.z, x2.y, ay);
    az = fmaf(w4.z, x2.z, az); aw = fmaf(w4.z, x2.w, aw);
    ax = fmaf(w4.w, x3.x, ax); ay = fmaf(w4.w, x3.y, ay);
    az = fmaf(w4.w, x3.z, az); aw = fmaf(w4.w, x3.w, aw);
  }
  // fold the 4 c-quarters (lane bits 0..1)
  ax += __shfl_xor(ax, 1, 64); ax += __shfl_xor(ax, 2, 64);
  ay += __shfl_xor(ay, 1, 64); ay += __shfl_xor(ay, 2, 64);
  az += __shfl_xor(az, 1, 64); az += __shfl_xor(az, 2, 64);
  aw += __shfl_xor(aw, 1, 64); aw += __shfl_xor(aw, 2, 64);
  if (cq == 0) {
    ls[k][0] = ax * rnx;
    ls[k][1] = ay * rny;
    ls[k][2] = az * rnz;
    ls[k][3] = aw * rnw;
  }
  __syncthreads();

  // softmax over K: wave wv handles pixel wv; lane indexes k
  {
    const float v = ls[lane][wv];
    float mx = v;
    #pragma unroll
    for (int m = 1; m < 64; m <<= 1) mx = fmaxf(mx, __shfl_xor(mx, m, 64));
    const float e = expf(v - mx);
    float s = e;
    #pragma unroll
    for (int m = 1; m < 64; m <<= 1) s += __shfl_xor(s, m, 64);
    sa[((size_t)n*K_ + lane)*HW_ + rem + wv] = e / s;
  }
}

// ---------------------------------------------------------------------------
// K2: out[n, k*C+c, i, j] = box5x5((xn'[c]-cent[k,c]/25)*sa[k])
// thread = (c, w). Vertical 5-window via register slide; horizontal 5-tap
// via fused v_add_f32_dpp chain + one ds_swizzle for the 16-row boundary.
// ---------------------------------------------------------------------------
__global__ __launch_bounds__(256) void k2_box(
    const float* __restrict__ xn, const float* __restrict__ sa,
    const float* __restrict__ cent, float* __restrict__ out)
{
  const int tid = threadIdx.x;
  const int w   = tid & 31;
  const int wc  = (w < W_) ? w : (W_ - 1);   // clamp pad lanes 30,31
  const int c   = (blockIdx.x << 3) + (tid >> 5);
  const int k   = blockIdx.y;
  const int n   = blockIdx.z;

  const float cv25 = cent[k*C_ + c] * INV25;
  const float* __restrict__ xp = xn + (size_t)(n*C_ + c)*HW_ + wc;
  const float* __restrict__ sp = sa + (size_t)(n*K_ + k)*HW_ + wc;

  float q[H_];
  #pragma unroll
  for (int h = 0; h < H_; ++h) {
    q[h] = (xp[h*W_] - cv25) * sp[h*W_];
  }

  float vq = q[0] + q[1] + q[2] + q[3] + q[4];  // vertical 5-window sum
  float* __restrict__ op = out + (size_t)((n*K_ + k)*C_ + c)*OHW_ + w;

  #pragma unroll
  for (int i = 0; i < OH_; ++i) {
    // hs[w] = sum_{d=0..4} vq[w+d]; serial single-use-DPP chain so each
    // term fuses to v_add_f32_dpp. Cross-16-row part from swz(x16).
    const float sw = swz_x16(vq);
    float hs = vq;
    hs += dpp0f<0x101>(vq);   // +vq[w+1] (in-row)
    hs += dpp0f<0x102>(vq);   // +vq[w+2]
    hs += dpp0f<0x103>(vq);   // +vq[w+3]
    hs += dpp0f<0x104>(vq);   // +vq[w+4]
    hs += dpp0f<0x11F>(sw);   // cross-row d=1
    hs += dpp0f<0x11E>(sw);   // cross-row d=2
    hs += dpp0f<0x11D>(sw);   // cross-row d=3
    hs += dpp0f<0x11C>(sw);   // cross-row d=4
    if (w < OW_) __builtin_nontemporal_store(hs, &op[i*OW_]);
    if (i < OH_ - 1) vq += q[i + P_] - q[i];
  }
}

extern "C" void kernel_launch(void* const* d_in, const int* in_sizes, int n_in,
                              void* d_out, int out_size, void* d_ws, size_t ws_size,
                              hipStream_t stream) {
  const float* x  = (const float*)d_in[0];
  const float* cw = (const float*)d_in[1];  // [K,C]
  const float* ce = (const float*)d_in[2];  // [K,C]
  // d_in[3]=patch_size(5), d_in[4]=stride(1): fixed by setup, hardcoded.

  float* xn = (float*)d_ws;                 // 4*128*1200 f32 (pre-scaled /25)
  float* sa = xn + (size_t)N_*C_*HW_;       // 4*64*1200 f32
  float* out = (float*)d_out;

  k1_prep<<<dim3(1200), dim3(256), 0, stream>>>(x, cw, xn, sa);
  k2_box<<<dim3(C_/8, K_, N_), dim3(256), 0, stream>>>(xn, sa, ce, out);
}

// Round 3
// 51.210 us; speedup vs baseline: 1.7962x; 1.7962x over previous
//
#include <hip/hip_runtime.h>

#define C_ 128
#define K_ 64
#define H_ 40
#define W_ 30
#define N_ 4
#define HW_ 1200          // H_*W_
#define P_ 5
#define OH_ 36            // H_+1-P_
#define OW_ 26            // W_+1-P_
#define OHW_ 936

// DPP helper: returns value moved per CTRL, 0-filled at row bounds.
// row_shl:N = 0x100+N ; row_shr:N = 0x110+N  (16-lane rows, bound_ctrl=0)
template<int CTRL>
__device__ __forceinline__ float dpp0f(float v) {
  return __int_as_float(__builtin_amdgcn_update_dpp(
      0, __float_as_int(v), CTRL, 0xF, 0xF, true));
}
// swap 16-lane rows pairwise (lane ^= 16)
__device__ __forceinline__ float swz_x16(float v) {
  return __int_as_float(__builtin_amdgcn_ds_swizzle(__float_as_int(v), 0x401F));
}

// ---------------------------------------------------------------------------
// K1 v4: R1 algorithm, tile shrunk 32->8 pixels/block for occupancy.
// 600 blocks x 256 threads (~2.3 blocks/CU vs R1's 0.6).
// Phases: stage(x,wt) -> norms -> conv (2 k's/thread, float2 LDS) -> softmax.
// ---------------------------------------------------------------------------
__global__ __launch_bounds__(256) void k1_prep(
    const float* __restrict__ x, const float* __restrict__ cw,
    float* __restrict__ xn, float* __restrict__ sa)
{
  __shared__ float xs[C_][8];       // 4 KB   x values, [c][pixel]
  __shared__ float wt[C_][66];      // 33.8KB conv_w transposed, pad 64->66
  __shared__ float part[32][8];     // 1 KB   partial norm sums
  __shared__ float ls[K_][9];       // 2.3KB  logits, pad 8->9
  __shared__ float rnorm_s[8];

  const int tid = threadIdx.x;
  const int bid = blockIdx.x;
  const int n   = bid / 150;
  const int rem = (bid - n*150) * 8;          // 8 contiguous pixels

  // stage conv_w transposed: wt[c][k] = cw[k*C_+c]
  for (int e = tid; e < C_*K_; e += 256) {
    const int c = e >> 6, kk = e & 63;
    wt[c][kk] = cw[kk*C_ + c];
  }
  // stage x for 8 pixels
  for (int e = tid; e < C_*8; e += 256) {
    const int c = e >> 3, p2 = e & 7;
    xs[c][p2] = x[((size_t)n*C_ + c)*HW_ + rem + p2];
  }
  __syncthreads();

  const int pl = tid & 7;           // pixel 0..7
  const int kq = tid >> 3;          // 0..31
  // partial norms: thread (kq,pl) sums 4 channels
  {
    float s = 0.f;
    #pragma unroll
    for (int cc = 0; cc < 4; ++cc) {
      const float v = xs[kq*4 + cc][pl];
      s = fmaf(v, v, s);
    }
    part[kq][pl] = s;
  }
  __syncthreads();
  if (tid < 8) {
    float s = 0.f;
    #pragma unroll
    for (int q = 0; q < 32; ++q) s += part[q][tid];
    rnorm_s[tid] = 1.f / fmaxf(sqrtf(s), 1e-12f);
  }
  __syncthreads();

  // conv: thread (kq,pl) computes k = 2kq, 2kq+1 for pixel pl
  {
    float a0 = 0.f, a1 = 0.f;
    #pragma unroll 8
    for (int c = 0; c < C_; ++c) {
      const float xv = xs[c][pl];
      const float2 w2 = *(const float2*)&wt[c][kq*2];
      a0 = fmaf(xv, w2.x, a0);
      a1 = fmaf(xv, w2.y, a1);
    }
    const float rn = rnorm_s[pl];
    ls[kq*2 + 0][pl] = a0 * rn;
    ls[kq*2 + 1][pl] = a1 * rn;
  }
  // write xn (unscaled; k2 applies 1/25 at store)
  for (int e = tid; e < C_*8; e += 256) {
    const int c = e >> 3, p2 = e & 7;
    xn[((size_t)n*C_ + c)*HW_ + rem + p2] = xs[c][p2] * rnorm_s[p2];
  }
  __syncthreads();

  // softmax over K: wave wv handles pixels wv and wv+4; lane indexes k
  const int lane = tid & 63;
  const int wv   = tid >> 6;
  #pragma unroll
  for (int r = 0; r < 2; ++r) {
    const int p = wv + (r << 2);
    const float v = ls[lane][p];
    float mx = v;
    #pragma unroll
    for (int m = 1; m < 64; m <<= 1) mx = fmaxf(mx, __shfl_xor(mx, m, 64));
    const float e = expf(v - mx);
    float s = e;
    #pragma unroll
    for (int m = 1; m < 64; m <<= 1) s += __shfl_xor(s, m, 64);
    sa[((size_t)n*K_ + lane)*HW_ + rem + p] = e / s;
  }
}

// ---------------------------------------------------------------------------
// K2: verbatim R1 (proven). out = box5x5((xn[c]-cent[k,c])*sa[k]) / 25
// ---------------------------------------------------------------------------
__global__ __launch_bounds__(256) void k2_box(
    const float* __restrict__ xn, const float* __restrict__ sa,
    const float* __restrict__ cent, float* __restrict__ out)
{
  const int tid = threadIdx.x;
  const int w   = tid & 31;
  const int wc  = (w < W_) ? w : (W_ - 1);   // clamp pad lanes 30,31
  const int c   = (blockIdx.x << 3) + (tid >> 5);
  const int k   = blockIdx.y;
  const int n   = blockIdx.z;

  const float cv = cent[k*C_ + c];
  const float* __restrict__ xp = xn + (size_t)(n*C_ + c)*HW_ + wc;
  const float* __restrict__ sp = sa + (size_t)(n*K_ + k)*HW_ + wc;

  float q[H_];
  #pragma unroll
  for (int h = 0; h < H_; ++h) {
    q[h] = (xp[h*W_] - cv) * sp[h*W_];
  }

  float vq = q[0] + q[1] + q[2] + q[3] + q[4];  // vertical 5-window sum
  float* __restrict__ op = out + (size_t)((n*K_ + k)*C_ + c)*OHW_ + w;

  #pragma unroll
  for (int i = 0; i < OH_; ++i) {
    const float sw = swz_x16(vq);
    float hs = vq;
    hs += dpp0f<0x101>(vq) + dpp0f<0x11F>(sw);  // d=1
    hs += dpp0f<0x102>(vq) + dpp0f<0x11E>(sw);  // d=2
    hs += dpp0f<0x103>(vq) + dpp0f<0x11D>(sw);  // d=3
    hs += dpp0f<0x104>(vq) + dpp0f<0x11C>(sw);  // d=4
    if (w < OW_) op[i*OW_] = hs * (1.f / (P_*P_));
    if (i < OH_ - 1) vq += q[i + P_] - q[i];
  }
}

extern "C" void kernel_launch(void* const* d_in, const int* in_sizes, int n_in,
                              void* d_out, int out_size, void* d_ws, size_t ws_size,
                              hipStream_t stream) {
  const float* x  = (const float*)d_in[0];
  const float* cw = (const float*)d_in[1];  // [K,C]
  const float* ce = (const float*)d_in[2];  // [K,C]
  // d_in[3]=patch_size(5), d_in[4]=stride(1): fixed by setup, hardcoded.

  float* xn = (float*)d_ws;                 // 4*128*1200 f32
  float* sa = xn + (size_t)N_*C_*HW_;       // 4*64*1200 f32
  float* out = (float*)d_out;

  k1_prep<<<dim3(600), dim3(256), 0, stream>>>(x, cw, xn, sa);
  k2_box<<<dim3(C_/8, K_, N_), dim3(256), 0, stream>>>(xn, sa, ce, out);
}

// Round 4
// 46.041 us; speedup vs baseline: 1.9979x; 1.1123x over previous
//
#include <hip/hip_runtime.h>

#define C_ 128
#define K_ 64
#define H_ 40
#define W_ 30
#define N_ 4
#define HW_ 1200          // H_*W_
#define P_ 5
#define OH_ 36            // H_+1-P_
#define OW_ 26            // W_+1-P_
#define OHW_ 936

// DPP helper: returns value moved per CTRL, 0-filled at row bounds.
// row_shl:N = 0x100+N ; row_shr:N = 0x110+N  (16-lane rows, bound_ctrl=0)
template<int CTRL>
__device__ __forceinline__ float dpp0f(float v) {
  return __int_as_float(__builtin_amdgcn_update_dpp(
      0, __float_as_int(v), CTRL, 0xF, 0xF, true));
}
// swap 16-lane rows pairwise (lane ^= 16)
__device__ __forceinline__ float swz_x16(float v) {
  return __int_as_float(__builtin_amdgcn_ds_swizzle(__float_as_int(v), 0x401F));
}

// ---------------------------------------------------------------------------
// K1: verbatim R1 (proven, ~5us). 32 pixels/block, 150 blocks.
// ---------------------------------------------------------------------------
__global__ __launch_bounds__(256) void k1_prep(
    const float* __restrict__ x, const float* __restrict__ cw,
    float* __restrict__ xn, float* __restrict__ sa)
{
  __shared__ float xs[C_][32];      // 16 KB  x values, [c][pixel]
  __shared__ float wt[C_][K_];      // 32 KB  conv_w transposed
  __shared__ float part[8][32];     // partial norm sums
  __shared__ float ls[K_][32];      // logits then exp values
  __shared__ float rnorm_s[32];
  __shared__ float rsum_s[32];

  const int tid  = threadIdx.x;
  const int pix0 = blockIdx.x << 5;

  for (int e = tid; e < C_*K_; e += 256) {
    const int c = e >> 6, kk = e & 63;
    wt[c][kk] = cw[kk*C_ + c];
  }
  for (int e = tid; e < C_*32; e += 256) {
    const int c = e >> 5, pl = e & 31;
    const int pix = pix0 + pl;
    const int n = pix / HW_, rem = pix - n*HW_;
    xs[c][pl] = x[(size_t)(n*C_ + c)*HW_ + rem];
  }
  __syncthreads();
  {
    const int pl = tid & 31, cq = tid >> 5;
    float s = 0.f;
    #pragma unroll
    for (int cc = 0; cc < 16; ++cc) {
      const float v = xs[cq*16 + cc][pl];
      s = fmaf(v, v, s);
    }
    part[cq][pl] = s;
  }
  __syncthreads();
  if (tid < 32) {
    float s = 0.f;
    #pragma unroll
    for (int qq = 0; qq < 8; ++qq) s += part[qq][tid];
    rnorm_s[tid] = 1.f / fmaxf(sqrtf(s), 1e-12f);
  }
  __syncthreads();
  {
    const int pl = tid & 31, kq = tid >> 5;
    float acc[8];
    #pragma unroll
    for (int qq = 0; qq < 8; ++qq) acc[qq] = 0.f;
    for (int c = 0; c < C_; ++c) {
      const float xv = xs[c][pl];
      const float4 w0 = *(const float4*)&wt[c][kq*8];
      const float4 w1 = *(const float4*)&wt[c][kq*8 + 4];
      acc[0] = fmaf(xv, w0.x, acc[0]);
      acc[1] = fmaf(xv, w0.y, acc[1]);
      acc[2] = fmaf(xv, w0.z, acc[2]);
      acc[3] = fmaf(xv, w0.w, acc[3]);
      acc[4] = fmaf(xv, w1.x, acc[4]);
      acc[5] = fmaf(xv, w1.y, acc[5]);
      acc[6] = fmaf(xv, w1.z, acc[6]);
      acc[7] = fmaf(xv, w1.w, acc[7]);
    }
    const float rn = rnorm_s[pl];
    #pragma unroll
    for (int qq = 0; qq < 8; ++qq) ls[kq*8 + qq][pl] = acc[qq] * rn;
  }
  __syncthreads();
  if (tid < 32) {
    const int pl = tid;
    float m = -1e30f;
    for (int kk = 0; kk < K_; ++kk) m = fmaxf(m, ls[kk][pl]);
    float s = 0.f;
    for (int kk = 0; kk < K_; ++kk) {
      const float e = expf(ls[kk][pl] - m);
      ls[kk][pl] = e;
      s += e;
    }
    rsum_s[pl] = 1.f / s;
  }
  __syncthreads();
  for (int e = tid; e < K_*32; e += 256) {
    const int kk = e >> 5, pl = e & 31;
    const int pix = pix0 + pl;
    const int n = pix / HW_, rem = pix - n*HW_;
    sa[(size_t)(n*K_ + kk)*HW_ + rem] = ls[kk][pl] * rsum_s[pl];
  }
  for (int e = tid; e < C_*32; e += 256) {
    const int c = e >> 5, pl = e & 31;
    const int pix = pix0 + pl;
    const int n = pix / HW_, rem = pix - n*HW_;
    xn[(size_t)(n*C_ + c)*HW_ + rem] = xs[c][pl] * rnorm_s[pl];
  }
}

// ---------------------------------------------------------------------------
// K2 v3: R1 structure, row dim split in two. Thread = (c, w, row-half):
// 22 input rows -> 18 out rows. q[22] (was q[40]) -> VGPR down, occupancy up,
// 8192 blocks (was 4096). Same DPP horizontal 5-tap.
// ---------------------------------------------------------------------------
__global__ __launch_bounds__(256, 6) void k2_box(
    const float* __restrict__ xn, const float* __restrict__ sa,
    const float* __restrict__ cent, float* __restrict__ out)
{
  const int tid = threadIdx.x;
  const int w   = tid & 31;
  const int wc  = (w < W_) ? w : (W_ - 1);   // clamp pad lanes 30,31
  const int c   = (blockIdx.x << 3) + (tid >> 5);
  const int k   = blockIdx.y;
  const int nh  = blockIdx.z;
  const int n   = nh >> 1;
  const int r0  = (nh & 1) * 18;             // first input row of this half

  const float cv = cent[k*C_ + c];
  const float* __restrict__ xp = xn + (size_t)(n*C_ + c)*HW_ + (size_t)r0*W_ + wc;
  const float* __restrict__ sp = sa + (size_t)(n*K_ + k)*HW_ + (size_t)r0*W_ + wc;

  float q[22];
  #pragma unroll
  for (int h = 0; h < 22; ++h) {
    q[h] = (xp[h*W_] - cv) * sp[h*W_];
  }

  float vq = q[0] + q[1] + q[2] + q[3] + q[4];  // vertical 5-window sum
  float* __restrict__ op = out + (size_t)((n*K_ + k)*C_ + c)*OHW_
                               + (size_t)r0*OW_ + w;

  #pragma unroll
  for (int i = 0; i < 18; ++i) {
    const float sw = swz_x16(vq);
    float hs = vq;
    hs += dpp0f<0x101>(vq) + dpp0f<0x11F>(sw);  // d=1
    hs += dpp0f<0x102>(vq) + dpp0f<0x11E>(sw);  // d=2
    hs += dpp0f<0x103>(vq) + dpp0f<0x11D>(sw);  // d=3
    hs += dpp0f<0x104>(vq) + dpp0f<0x11C>(sw);  // d=4
    if (w < OW_) op[i*OW_] = hs * (1.f / (P_*P_));
    if (i < 17) vq += q[i + P_] - q[i];
  }
}

extern "C" void kernel_launch(void* const* d_in, const int* in_sizes, int n_in,
                              void* d_out, int out_size, void* d_ws, size_t ws_size,
                              hipStream_t stream) {
  const float* x  = (const float*)d_in[0];
  const float* cw = (const float*)d_in[1];  // [K,C]
  const float* ce = (const float*)d_in[2];  // [K,C]
  // d_in[3]=patch_size(5), d_in[4]=stride(1): fixed by setup, hardcoded.

  float* xn = (float*)d_ws;                 // 4*128*1200 f32
  float* sa = xn + (size_t)N_*C_*HW_;       // 4*64*1200 f32
  float* out = (float*)d_out;

  k1_prep<<<dim3(150), dim3(256), 0, stream>>>(x, cw, xn, sa);
  k2_box<<<dim3(C_/8, K_, N_*2), dim3(256), 0, stream>>>(xn, sa, ce, out);
}